// Round 2
// baseline (289.021 us; speedup 1.0000x reference)
//
#include <hip/hip_runtime.h>
#include <math.h>

#define HEADS 8
#define C 256
#define NUM_STAR 4
#define SLOTS 32              // NUM_STAR * HEADS
#define RSQRT_DH 0.17677669529663688f   // 1/sqrt(32)
#define LN_EPS 1e-5f
#define P1 32                 // score-kernel partitions per graph
#define P2 8                  // accum-kernel partitions per graph
#define CH 32                 // nodes per LDS chunk
#define XPAD 260              // padded row stride (floats) for x in LDS

// ---------------- graph start offsets: gstart[g] = lower_bound(batch, g) ----
__global__ void k_gstart(const int* __restrict__ batch, int N, int G,
                         int* __restrict__ gstart) {
    int g = threadIdx.x;
    if (g > G) return;
    if (g == 0) { gstart[0] = 0; return; }
    if (g == G) { gstart[G] = N; return; }
    int lo = 0, hi = N;
    while (lo < hi) {
        int mid = (lo + hi) >> 1;
        if (batch[mid] < g) lo = mid + 1; else hi = mid;
    }
    gstart[g] = lo;
}

// ---------------- per-star precompute: q, U = Wk_h^T q_h / sqrt(dh), self ----
__global__ void k_star_prep(const float* __restrict__ stars,
                            const float* __restrict__ Wq_w, const float* __restrict__ Wq_b,
                            const float* __restrict__ Wk_w, const float* __restrict__ Wk_b,
                            float* __restrict__ U, float* __restrict__ eself,
                            float* __restrict__ denom, float* __restrict__ Y) {
    __shared__ float xs[C];
    __shared__ float qv[C];
    __shared__ float kv[C];
    const int gs = blockIdx.x;           // g*4 + s
    const int g = gs >> 2, s = gs & 3;
    const int t = threadIdx.x;

    xs[t] = stars[gs * C + t];
    __syncthreads();

    // q[t], k[t] = row t of Wq/Wk dot x_star + bias
    float aq = Wq_b[t], ak = Wk_b[t];
    const float* wq = Wq_w + (size_t)t * C;
    const float* wk = Wk_w + (size_t)t * C;
    #pragma unroll 4
    for (int j = 0; j < C; j += 4) {
        float4 x4 = *(const float4*)(xs + j);
        float4 a4 = *(const float4*)(wq + j);
        aq += a4.x * x4.x + a4.y * x4.y + a4.z * x4.z + a4.w * x4.w;
        float4 b4 = *(const float4*)(wk + j);
        ak += b4.x * x4.x + b4.y * x4.y + b4.z * x4.z + b4.w * x4.w;
    }
    qv[t] = aq; kv[t] = ak;
    __syncthreads();

    // self score per head: reduce q*k over 32 lanes
    {
        float p = qv[t] * kv[t];
        #pragma unroll
        for (int off = 16; off; off >>= 1) p += __shfl_down(p, off, 32);
        if ((t & 31) == 0) {
            int h = t >> 5;
            float e = __expf(p * RSQRT_DH);
            eself[g * SLOTS + s * HEADS + h] = e;
            denom[g * SLOTS + s * HEADS + h] = e;   // init with self term
        }
    }

    // U[(g*C + c)*SLOTS + s*8 + h] = (1/sqrt(dh)) * sum_d Wk[h*32+d][c] * q[h*32+d]
    {
        const int c = t;
        #pragma unroll
        for (int h = 0; h < HEADS; ++h) {
            float u = 0.f;
            for (int d = 0; d < 32; ++d)
                u += Wk_w[(size_t)(h * 32 + d) * C + c] * qv[h * 32 + d];
            U[((size_t)g * C + c) * SLOTS + s * HEADS + h] = u * RSQRT_DH;
        }
    }

    // zero Y for this (g,s)
    for (int i = t; i < HEADS * C; i += 256) {
        int h = i >> 8, j = i & 255;
        Y[((size_t)g * SLOTS + s * HEADS + h) * C + j] = 0.f;
    }
}

// ---------------- K1: scores + exp + denom ---------------------------------
__global__ __launch_bounds__(256, 2)
void k_scores(const float* __restrict__ nodes, const float* __restrict__ U,
              const int* __restrict__ gstart, float* __restrict__ E,
              float* __restrict__ denom) {
    __shared__ float U_lds[C * SLOTS];      // 32 KB, [c][slot]
    __shared__ float x_lds[CH * XPAD];      // 33.3 KB, [node][c] (also aliased as red)
    __shared__ float dsum[SLOTS];

    const int g = blockIdx.x / P1, p = blockIdx.x % P1;
    const int t = threadIdx.x;
    const int glo = gstart[g], ghi = gstart[g + 1];
    const int len = ghi - glo;
    const int L = (len + P1 - 1) / P1;
    const int lo = glo + p * L;
    const int hi = min(lo + L, ghi);
    if (lo >= hi) return;

    for (int i = t * 4; i < C * SLOTS; i += 256 * 4)
        *(float4*)&U_lds[i] = *(const float4*)&U[(size_t)g * C * SLOTS + i];
    if (t < SLOTS) dsum[t] = 0.f;
    __syncthreads();

    const int node = t & 31;       // 0..31
    const int cpart = t >> 5;      // 0..7  (32 channels each)

    for (int clo = lo; clo < hi; clo += CH) {
        __syncthreads();           // prev red reads done before restaging x
        // stage x chunk: [node][c] padded, coalesced global reads
        #pragma unroll
        for (int k = 0; k < 8; ++k) {
            int f = k * 256 + t;
            int nl = f >> 6;
            int cc = (f & 63) * 4;
            int gn = clo + nl;
            float4 v = (gn < hi) ? *(const float4*)&nodes[(size_t)gn * C + cc]
                                 : make_float4(0.f, 0.f, 0.f, 0.f);
            *(float4*)&x_lds[nl * XPAD + cc] = v;
        }
        __syncthreads();

        // scores: each thread: its node, its 32-channel slice, all 32 slots
        float acc[32];
        #pragma unroll
        for (int i = 0; i < 32; ++i) acc[i] = 0.f;
        const float* xrow = &x_lds[node * XPAD + cpart * 32];
        const float* ub = &U_lds[cpart * 32 * SLOTS];
        #pragma unroll
        for (int c4 = 0; c4 < 8; ++c4) {
            float4 xv = *(const float4*)&xrow[c4 * 4];
            float xa[4] = {xv.x, xv.y, xv.z, xv.w};
            #pragma unroll
            for (int i = 0; i < 4; ++i) {
                const float xsv = xa[i];
                const float* ur = &ub[(c4 * 4 + i) * SLOTS];
                #pragma unroll
                for (int s4 = 0; s4 < 8; ++s4) {
                    float4 uv = *(const float4*)&ur[s4 * 4];
                    acc[s4 * 4 + 0] += xsv * uv.x;
                    acc[s4 * 4 + 1] += xsv * uv.y;
                    acc[s4 * 4 + 2] += xsv * uv.z;
                    acc[s4 * 4 + 3] += xsv * uv.w;
                }
            }
        }
        __syncthreads();           // x reads done -> safe to overwrite (alias)

        // partial reduce across the 8 channel-parts via LDS (aliased over x_lds)
        float* red = x_lds;        // [8][32 nodes][32 slots], bank-swizzled
        {
            const int base = cpart * 1024 + node * 32;
            #pragma unroll
            for (int s4 = 0; s4 < 8; ++s4) {
                int pos = ((s4 ^ (node & 7)) * 4);
                *(float4*)&red[base + pos] =
                    make_float4(acc[s4 * 4 + 0], acc[s4 * 4 + 1],
                                acc[s4 * 4 + 2], acc[s4 * 4 + 3]);
            }
        }
        __syncthreads();
        {
            const int nr = t >> 3;       // node 0..31
            const int s4r = t & 7;       // slot group
            const int gn = clo + nr;
            const int rb = nr * 32 + ((s4r ^ (nr & 7)) * 4);
            float4 sc = make_float4(0.f, 0.f, 0.f, 0.f);
            #pragma unroll
            for (int pp = 0; pp < 8; ++pp) {
                float4 v = *(const float4*)&red[pp * 1024 + rb];
                sc.x += v.x; sc.y += v.y; sc.z += v.z; sc.w += v.w;
            }
            if (gn < hi) {
                float4 e;
                e.x = __expf(sc.x); e.y = __expf(sc.y);
                e.z = __expf(sc.z); e.w = __expf(sc.w);
                *(float4*)&E[(size_t)gn * SLOTS + s4r * 4] = e;
                atomicAdd(&dsum[s4r * 4 + 0], e.x);
                atomicAdd(&dsum[s4r * 4 + 1], e.y);
                atomicAdd(&dsum[s4r * 4 + 2], e.z);
                atomicAdd(&dsum[s4r * 4 + 3], e.w);
            }
        }
    }
    __syncthreads();
    if (t < SLOTS) atomicAdd(&denom[g * SLOTS + t], dsum[t]);
}

// ---------------- K2: y[g][slot][c] = sum_e coef * x_e ---------------------
__global__ __launch_bounds__(256, 4)
void k_accum(const float* __restrict__ nodes, const float* __restrict__ E,
             const float* __restrict__ denom, const int* __restrict__ gstart,
             float* __restrict__ Y) {
    __shared__ float x_lds[CH * XPAD];      // 33.3 KB
    __shared__ float E_lds[CH * SLOTS];     // 4 KB
    __shared__ float invd[SLOTS];

    const int g = blockIdx.x / P2, p = blockIdx.x % P2;
    const int t = threadIdx.x;
    const int glo = gstart[g], ghi = gstart[g + 1];
    const int len = ghi - glo;
    const int L = (len + P2 - 1) / P2;
    const int lo = glo + p * L;
    const int hi = min(lo + L, ghi);
    if (lo >= hi) return;

    if (t < SLOTS) invd[t] = 1.f / (denom[g * SLOTS + t] + 1e-16f);
    __syncthreads();

    const int slot = t & 31;
    const int cg = t >> 5;                  // channel group, c0 = cg*32
    const float iv = invd[slot];

    float y[32];
    #pragma unroll
    for (int i = 0; i < 32; ++i) y[i] = 0.f;

    for (int clo = lo; clo < hi; clo += CH) {
        __syncthreads();
        #pragma unroll
        for (int k = 0; k < 8; ++k) {
            int f = k * 256 + t;
            int nl = f >> 6;
            int cc = (f & 63) * 4;
            int gn = clo + nl;
            float4 v = (gn < hi) ? *(const float4*)&nodes[(size_t)gn * C + cc]
                                 : make_float4(0.f, 0.f, 0.f, 0.f);
            *(float4*)&x_lds[nl * XPAD + cc] = v;
        }
        {
            int idx = t * 4;
            int nl = idx >> 5;
            float4 v = (clo + nl < hi)
                ? *(const float4*)&E[(size_t)(clo + nl) * SLOTS + (idx & 31)]
                : make_float4(0.f, 0.f, 0.f, 0.f);
            *(float4*)&E_lds[idx] = v;
        }
        __syncthreads();

        const int nmax = min(CH, hi - clo);
        for (int n = 0; n < nmax; ++n) {
            float coef = E_lds[n * SLOTS + slot] * iv;
            const float* xr = &x_lds[n * XPAD + cg * 32];
            #pragma unroll
            for (int j4 = 0; j4 < 8; ++j4) {
                float4 xv = *(const float4*)&xr[j4 * 4];
                y[j4 * 4 + 0] += coef * xv.x;
                y[j4 * 4 + 1] += coef * xv.y;
                y[j4 * 4 + 2] += coef * xv.z;
                y[j4 * 4 + 3] += coef * xv.w;
            }
        }
    }
    // flush
    float* yg = &Y[((size_t)g * SLOTS + slot) * C + cg * 32];
    #pragma unroll
    for (int j = 0; j < 32; ++j) atomicAdd(&yg[j], y[j]);
}

// ---------------- K3: out = LN(elu(Wv*y + bv) + stars) ---------------------
__global__ void k_epilogue(const float* __restrict__ stars,
                           const float* __restrict__ Wv_w, const float* __restrict__ Wv_b,
                           const float* __restrict__ gamma, const float* __restrict__ beta,
                           const float* __restrict__ Y, const float* __restrict__ eself,
                           const float* __restrict__ denom, float* __restrict__ out) {
    __shared__ float xs[C];
    __shared__ float yl[HEADS * C];
    __shared__ float cs[HEADS], scl[HEADS];
    __shared__ float rb[8];

    const int gs = blockIdx.x;
    const int g = gs >> 2, s = gs & 3;
    const int t = threadIdx.x;

    xs[t] = stars[gs * C + t];
    if (t < HEADS) {
        float dn = denom[g * SLOTS + s * HEADS + t];
        float iv = 1.f / (dn + 1e-16f);
        cs[t] = eself[g * SLOTS + s * HEADS + t] * iv;
        scl[t] = dn * iv;     // = sum of coefficients (~1)
    }
    __syncthreads();

    // Y is ALREADY normalized (coef = e/denom applied in k_accum) —
    // only add the self-loop contribution coef_self * x_star here.
    for (int i = t; i < HEADS * C; i += 256) {
        int h = i >> 8, j = i & 255;
        yl[i] = Y[((size_t)g * SLOTS + s * HEADS + h) * C + j] + cs[h] * xs[j];
    }
    __syncthreads();

    const int c = t, h = c >> 5;
    float a = 0.f;
    const float* wv = Wv_w + (size_t)c * C;
    const float* yh = &yl[h * C];
    #pragma unroll 4
    for (int j = 0; j < C; j += 4) {
        float4 w4 = *(const float4*)(wv + j);
        float4 y4 = *(const float4*)(yh + j);
        a += w4.x * y4.x + w4.y * y4.y + w4.z * y4.z + w4.w * y4.w;
    }
    a += Wv_b[c] * scl[h];

    float v = a > 0.f ? a : (__expf(a) - 1.f);     // ELU
    float r = v + xs[c];                            // residual

    // LayerNorm over 256 threads
    float ssum = r;
    #pragma unroll
    for (int off = 32; off; off >>= 1) ssum += __shfl_down(ssum, off, 64);
    const int wid = t >> 6, lane = t & 63;
    if (lane == 0) rb[wid] = ssum;
    __syncthreads();
    const float mu = (rb[0] + rb[1] + rb[2] + rb[3]) * (1.f / 256.f);
    const float d = r - mu;
    float vsum = d * d;
    #pragma unroll
    for (int off = 32; off; off >>= 1) vsum += __shfl_down(vsum, off, 64);
    if (lane == 0) rb[4 + wid] = vsum;
    __syncthreads();
    const float var = (rb[4] + rb[5] + rb[6] + rb[7]) * (1.f / 256.f);
    out[gs * C + c] = d * rsqrtf(var + LN_EPS) * gamma[c] + beta[c];
}

// ---------------------------------------------------------------------------
extern "C" void kernel_launch(void* const* d_in, const int* in_sizes, int n_in,
                              void* d_out, int out_size, void* d_ws, size_t ws_size,
                              hipStream_t stream) {
    const float* stars = (const float*)d_in[0];
    const float* nodes = (const float*)d_in[1];
    const int*   batch = (const int*)d_in[2];
    const float* Wq_w  = (const float*)d_in[3];
    const float* Wq_b  = (const float*)d_in[4];
    const float* Wk_w  = (const float*)d_in[5];
    const float* Wk_b  = (const float*)d_in[6];
    const float* Wv_w  = (const float*)d_in[7];
    const float* Wv_b  = (const float*)d_in[8];
    const float* gamma = (const float*)d_in[9];
    const float* beta  = (const float*)d_in[10];

    const int N = in_sizes[1] / C;
    const int G = in_sizes[0] / (NUM_STAR * C);

    float* ws    = (float*)d_ws;
    float* U     = ws;                                  // G*C*SLOTS
    float* eself = U + (size_t)G * C * SLOTS;           // G*SLOTS
    float* denom = eself + (size_t)G * SLOTS;           // G*SLOTS
    float* Y     = denom + (size_t)G * SLOTS;           // G*SLOTS*C
    float* E     = Y + (size_t)G * SLOTS * C;           // N*SLOTS
    int*   gstart = (int*)(E + (size_t)N * SLOTS);      // G+1

    float* out = (float*)d_out;

    k_gstart<<<1, 64, 0, stream>>>(batch, N, G, gstart);
    k_star_prep<<<G * NUM_STAR, 256, 0, stream>>>(stars, Wq_w, Wq_b, Wk_w, Wk_b,
                                                  U, eself, denom, Y);
    k_scores<<<G * P1, 256, 0, stream>>>(nodes, U, gstart, E, denom);
    k_accum<<<G * P2, 256, 0, stream>>>(nodes, E, denom, gstart, Y);
    k_epilogue<<<G * NUM_STAR, 256, 0, stream>>>(stars, Wv_w, Wv_b, gamma, beta,
                                                 Y, eself, denom, out);
}

// Round 3
// 275.758 us; speedup vs baseline: 1.0481x; 1.0481x over previous
//
#include <hip/hip_runtime.h>
#include <math.h>

#define HEADS 8
#define C 256
#define NUM_STAR 4
#define SLOTS 32              // NUM_STAR * HEADS
#define RSQRT_DH 0.17677669529663688f   // 1/sqrt(32)
#define LN_EPS 1e-5f
#define PF 16                 // fused-kernel partitions per graph
#define CH 32                 // nodes per LDS chunk
#define XB 264                // bf16 row stride (ushorts) for x in LDS (528 B, 16B-mult)
#define RW 40                 // red row stride (floats), 160 B = 16B-mult
#define EW 36                 // e row stride (floats), 144 B = 16B-mult

// ---------------- graph start offsets: gstart[g] = lower_bound(batch, g) ----
__global__ void k_gstart(const int* __restrict__ batch, int N, int G,
                         int* __restrict__ gstart) {
    int g = threadIdx.x;
    if (g > G) return;
    if (g == 0) { gstart[0] = 0; return; }
    if (g == G) { gstart[G] = N; return; }
    int lo = 0, hi = N;
    while (lo < hi) {
        int mid = (lo + hi) >> 1;
        if (batch[mid] < g) lo = mid + 1; else hi = mid;
    }
    gstart[g] = lo;
}

// ---------------- per-star precompute: q, U = Wk_h^T q_h / sqrt(dh), self ----
__global__ void k_star_prep(const float* __restrict__ stars,
                            const float* __restrict__ Wq_w, const float* __restrict__ Wq_b,
                            const float* __restrict__ Wk_w, const float* __restrict__ Wk_b,
                            float* __restrict__ U, float* __restrict__ eself,
                            float* __restrict__ denom, float* __restrict__ Y) {
    __shared__ float xs[C];
    __shared__ float qv[C];
    __shared__ float kv[C];
    const int gs = blockIdx.x;           // g*4 + s
    const int g = gs >> 2, s = gs & 3;
    const int t = threadIdx.x;

    xs[t] = stars[gs * C + t];
    __syncthreads();

    float aq = Wq_b[t], ak = Wk_b[t];
    const float* wq = Wq_w + (size_t)t * C;
    const float* wk = Wk_w + (size_t)t * C;
    #pragma unroll 4
    for (int j = 0; j < C; j += 4) {
        float4 x4 = *(const float4*)(xs + j);
        float4 a4 = *(const float4*)(wq + j);
        aq += a4.x * x4.x + a4.y * x4.y + a4.z * x4.z + a4.w * x4.w;
        float4 b4 = *(const float4*)(wk + j);
        ak += b4.x * x4.x + b4.y * x4.y + b4.z * x4.z + b4.w * x4.w;
    }
    qv[t] = aq; kv[t] = ak;
    __syncthreads();

    {
        float p = qv[t] * kv[t];
        #pragma unroll
        for (int off = 16; off; off >>= 1) p += __shfl_down(p, off, 32);
        if ((t & 31) == 0) {
            int h = t >> 5;
            float e = __expf(p * RSQRT_DH);
            eself[g * SLOTS + s * HEADS + h] = e;
            denom[g * SLOTS + s * HEADS + h] = e;   // init with self term
        }
    }

    {
        const int c = t;
        #pragma unroll
        for (int h = 0; h < HEADS; ++h) {
            float u = 0.f;
            for (int d = 0; d < 32; ++d)
                u += Wk_w[(size_t)(h * 32 + d) * C + c] * qv[h * 32 + d];
            U[((size_t)g * C + c) * SLOTS + s * HEADS + h] = u * RSQRT_DH;
        }
    }

    for (int i = t; i < HEADS * C; i += 256) {
        int h = i >> 8, j = i & 255;
        Y[((size_t)g * SLOTS + s * HEADS + h) * C + j] = 0.f;
    }
}

// f32 -> bf16 (RNE) top-16
__device__ __forceinline__ unsigned int f2b(float f) {
    unsigned int u = __float_as_uint(f);
    return (u + 0x7fffu + ((u >> 16) & 1u)) >> 16;
}

// ---------------- fused: scores + exp + denom + weighted accumulate ---------
__global__ __launch_bounds__(256, 2)
void k_fused(const float* __restrict__ nodes, const float* __restrict__ U,
             const int* __restrict__ gstart, float* __restrict__ denom,
             float* __restrict__ Y) {
    __shared__ float          U_lds[C * SLOTS];    // 32 KB   [c][slot]
    __shared__ unsigned short x_lds[CH * XB];      // 16.9 KB [n][c] bf16
    __shared__ float          red[4 * CH * RW];    // 20 KB   [wave][n][slot]
    __shared__ float          e_lds[CH * EW];      // 4.6 KB  [n][slot]

    const int g = blockIdx.x / PF, p = blockIdx.x % PF;
    const int t = threadIdx.x;
    const int glo = gstart[g], ghi = gstart[g + 1];
    const int len = ghi - glo;
    const int L = (len + PF - 1) / PF;
    const int lo = glo + p * L;
    const int hi = min(lo + L, ghi);
    if (lo >= hi) return;

    // stage U (per-graph, once)
    for (int i = t * 4; i < C * SLOTS; i += 256 * 4)
        *(float4*)&U_lds[i] = *(const float4*)&U[(size_t)g * C * SLOTS + i];

    const int sp = t >> 5;          // score phase: channel part 0..7
    const int sn = t & 31;          // score phase: node 0..31
    const int wv = t >> 6;          // wave id 0..3
    const int sg = t >> 5;          // accum: slot group (4 slots)
    const int cgr = t & 31;         // accum: channel group (8 ch)

    float y[4][8];
    float dsum[4];
    #pragma unroll
    for (int a = 0; a < 4; ++a) {
        dsum[a] = 0.f;
        #pragma unroll
        for (int b = 0; b < 8; ++b) y[a][b] = 0.f;
    }

    for (int clo = lo; clo < hi; clo += CH) {
        __syncthreads();   // prev accum done reading x/e; U staged (1st iter)

        // ---- stage x chunk as bf16 ----
        #pragma unroll
        for (int k = 0; k < 8; ++k) {
            int f = k * 256 + t;
            int nl = f >> 6;
            int cc = (f & 63) * 4;
            int gn = clo + nl;
            float4 v = (gn < hi) ? *(const float4*)&nodes[(size_t)gn * C + cc]
                                 : make_float4(0.f, 0.f, 0.f, 0.f);
            unsigned int w0 = f2b(v.x) | (f2b(v.y) << 16);
            unsigned int w1 = f2b(v.z) | (f2b(v.w) << 16);
            *(uint2*)&x_lds[nl * XB + cc] = make_uint2(w0, w1);
        }
        __syncthreads();

        // ---- score phase: thread (sp, sn), acc over its 32-channel slice ----
        float acc[32];
        #pragma unroll
        for (int i = 0; i < 32; ++i) acc[i] = 0.f;
        const unsigned short* xr = &x_lds[sn * XB + sp * 32];
        #pragma unroll
        for (int c8 = 0; c8 < 4; ++c8) {
            uint4 xp = *(const uint4*)(xr + c8 * 8);
            unsigned int uw[4] = {xp.x, xp.y, xp.z, xp.w};
            #pragma unroll
            for (int u2 = 0; u2 < 4; ++u2) {
                float xlo = __uint_as_float(uw[u2] << 16);
                float xhi = __uint_as_float(uw[u2] & 0xffff0000u);
                const float* ulo = &U_lds[(sp * 32 + c8 * 8 + u2 * 2) * SLOTS];
                const float* uhi = ulo + SLOTS;
                #pragma unroll
                for (int s4 = 0; s4 < 8; ++s4) {
                    float4 a4 = *(const float4*)(ulo + s4 * 4);
                    float4 b4 = *(const float4*)(uhi + s4 * 4);
                    acc[s4 * 4 + 0] += xlo * a4.x + xhi * b4.x;
                    acc[s4 * 4 + 1] += xlo * a4.y + xhi * b4.y;
                    acc[s4 * 4 + 2] += xlo * a4.z + xhi * b4.z;
                    acc[s4 * 4 + 3] += xlo * a4.w + xhi * b4.w;
                }
            }
        }
        // pre-reduce the two half-waves (cparts p and p^1)
        #pragma unroll
        for (int i = 0; i < 32; ++i) acc[i] += __shfl_xor(acc[i], 32, 64);
        if ((t & 63) < 32) {
            float* rr = &red[(wv * CH + sn) * RW];
            #pragma unroll
            for (int s4 = 0; s4 < 8; ++s4)
                *(float4*)&rr[s4 * 4] = make_float4(acc[s4 * 4 + 0], acc[s4 * 4 + 1],
                                                    acc[s4 * 4 + 2], acc[s4 * 4 + 3]);
        }
        __syncthreads();

        // ---- final reduce + exp -> e_lds; thread (n2, s4) ----
        {
            const int n2 = t >> 3, s4 = t & 7;
            float4 sum = make_float4(0.f, 0.f, 0.f, 0.f);
            #pragma unroll
            for (int w = 0; w < 4; ++w) {
                float4 v = *(const float4*)&red[(w * CH + n2) * RW + s4 * 4];
                sum.x += v.x; sum.y += v.y; sum.z += v.z; sum.w += v.w;
            }
            float4 e4;
            if (clo + n2 < hi) {
                e4.x = __expf(sum.x); e4.y = __expf(sum.y);
                e4.z = __expf(sum.z); e4.w = __expf(sum.w);
            } else {
                e4 = make_float4(0.f, 0.f, 0.f, 0.f);
            }
            *(float4*)&e_lds[n2 * EW + s4 * 4] = e4;
        }
        __syncthreads();

        // ---- accumulate phase: thread (sg, cgr): y += e * x ----
        const int nmax = min(CH, hi - clo);
        for (int n = 0; n < nmax; ++n) {
            float4 e4 = *(const float4*)&e_lds[n * EW + sg * 4];   // broadcast
            uint4 xp = *(const uint4*)&x_lds[n * XB + cgr * 8];    // 8 bf16 ch
            float xv[8];
            xv[0] = __uint_as_float(xp.x << 16);
            xv[1] = __uint_as_float(xp.x & 0xffff0000u);
            xv[2] = __uint_as_float(xp.y << 16);
            xv[3] = __uint_as_float(xp.y & 0xffff0000u);
            xv[4] = __uint_as_float(xp.z << 16);
            xv[5] = __uint_as_float(xp.z & 0xffff0000u);
            xv[6] = __uint_as_float(xp.w << 16);
            xv[7] = __uint_as_float(xp.w & 0xffff0000u);
            #pragma unroll
            for (int j = 0; j < 8; ++j) {
                y[0][j] += e4.x * xv[j];
                y[1][j] += e4.y * xv[j];
                y[2][j] += e4.z * xv[j];
                y[3][j] += e4.w * xv[j];
            }
            dsum[0] += e4.x; dsum[1] += e4.y; dsum[2] += e4.z; dsum[3] += e4.w;
        }
    }

    // ---- flush partials ----
    #pragma unroll
    for (int si = 0; si < 4; ++si) {
        float* yg = &Y[((size_t)g * SLOTS + sg * 4 + si) * C + cgr * 8];
        #pragma unroll
        for (int j = 0; j < 8; ++j) atomicAdd(&yg[j], y[si][j]);
    }
    if (cgr == 0) {
        #pragma unroll
        for (int si = 0; si < 4; ++si)
            atomicAdd(&denom[g * SLOTS + sg * 4 + si], dsum[si]);
    }
}

// ---------------- epilogue: out = LN(elu(Wv*(Y/denom + cself*x) + bv) + stars)
__global__ void k_epilogue(const float* __restrict__ stars,
                           const float* __restrict__ Wv_w, const float* __restrict__ Wv_b,
                           const float* __restrict__ gamma, const float* __restrict__ beta,
                           const float* __restrict__ Y, const float* __restrict__ eself,
                           const float* __restrict__ denom, float* __restrict__ out) {
    __shared__ float xs[C];
    __shared__ float yl[HEADS * C];
    __shared__ float cs[HEADS], ivd[HEADS], scl[HEADS];
    __shared__ float rb[8];

    const int gs = blockIdx.x;
    const int g = gs >> 2, s = gs & 3;
    const int t = threadIdx.x;

    xs[t] = stars[gs * C + t];
    if (t < HEADS) {
        float dn = denom[g * SLOTS + s * HEADS + t];
        float iv = 1.f / (dn + 1e-16f);
        ivd[t] = iv;
        cs[t] = eself[g * SLOTS + s * HEADS + t] * iv;
        scl[t] = dn * iv;     // = sum of coefficients (~1)
    }
    __syncthreads();

    // Y is UNNORMALIZED (sum of e*x) -> multiply by 1/denom here.
    for (int i = t; i < HEADS * C; i += 256) {
        int h = i >> 8, j = i & 255;
        yl[i] = Y[((size_t)g * SLOTS + s * HEADS + h) * C + j] * ivd[h] + cs[h] * xs[j];
    }
    __syncthreads();

    const int c = t, h = c >> 5;
    float a = 0.f;
    const float* wv = Wv_w + (size_t)c * C;
    const float* yh = &yl[h * C];
    #pragma unroll 4
    for (int j = 0; j < C; j += 4) {
        float4 w4 = *(const float4*)(wv + j);
        float4 y4 = *(const float4*)(yh + j);
        a += w4.x * y4.x + w4.y * y4.y + w4.z * y4.z + w4.w * y4.w;
    }
    a += Wv_b[c] * scl[h];

    float v = a > 0.f ? a : (__expf(a) - 1.f);     // ELU
    float r = v + xs[c];                            // residual

    float ssum = r;
    #pragma unroll
    for (int off = 32; off; off >>= 1) ssum += __shfl_down(ssum, off, 64);
    const int wid = t >> 6, lane = t & 63;
    if (lane == 0) rb[wid] = ssum;
    __syncthreads();
    const float mu = (rb[0] + rb[1] + rb[2] + rb[3]) * (1.f / 256.f);
    const float d = r - mu;
    float vsum = d * d;
    #pragma unroll
    for (int off = 32; off; off >>= 1) vsum += __shfl_down(vsum, off, 64);
    if (lane == 0) rb[4 + wid] = vsum;
    __syncthreads();
    const float var = (rb[4] + rb[5] + rb[6] + rb[7]) * (1.f / 256.f);
    out[gs * C + c] = d * rsqrtf(var + LN_EPS) * gamma[c] + beta[c];
}

// ---------------------------------------------------------------------------
extern "C" void kernel_launch(void* const* d_in, const int* in_sizes, int n_in,
                              void* d_out, int out_size, void* d_ws, size_t ws_size,
                              hipStream_t stream) {
    const float* stars = (const float*)d_in[0];
    const float* nodes = (const float*)d_in[1];
    const int*   batch = (const int*)d_in[2];
    const float* Wq_w  = (const float*)d_in[3];
    const float* Wq_b  = (const float*)d_in[4];
    const float* Wk_w  = (const float*)d_in[5];
    const float* Wk_b  = (const float*)d_in[6];
    const float* Wv_w  = (const float*)d_in[7];
    const float* Wv_b  = (const float*)d_in[8];
    const float* gamma = (const float*)d_in[9];
    const float* beta  = (const float*)d_in[10];

    const int N = in_sizes[1] / C;
    const int G = in_sizes[0] / (NUM_STAR * C);

    float* ws    = (float*)d_ws;
    float* U     = ws;                                  // G*C*SLOTS
    float* eself = U + (size_t)G * C * SLOTS;           // G*SLOTS
    float* denom = eself + (size_t)G * SLOTS;           // G*SLOTS
    float* Y     = denom + (size_t)G * SLOTS;           // G*SLOTS*C
    int*   gstart = (int*)(Y + (size_t)G * SLOTS * C);  // G+1

    float* out = (float*)d_out;

    k_gstart<<<1, 64, 0, stream>>>(batch, N, G, gstart);
    k_star_prep<<<G * NUM_STAR, 256, 0, stream>>>(stars, Wq_w, Wq_b, Wk_w, Wk_b,
                                                  U, eself, denom, Y);
    k_fused<<<G * PF, 256, 0, stream>>>(nodes, U, gstart, denom, Y);
    k_epilogue<<<G * NUM_STAR, 256, 0, stream>>>(stars, Wv_w, Wv_b, gamma, beta,
                                                 Y, eself, denom, out);
}

// Round 4
// 73.665 us; speedup vs baseline: 3.9234x; 3.7434x over previous
//
#include <hip/hip_runtime.h>
#include <math.h>

#define HEADS 8
#define C 256
#define NUM_STAR 4
#define SLOTS 32              // NUM_STAR * HEADS
#define RSQRT_DH 0.17677669529663688f   // 1/sqrt(32)
#define LN_EPS 1e-5f
#define PF 8                  // fused-kernel partitions per graph (grid = G*PF = 256)
#define CWK 16                // nodes per wave chunk
#define RND 64                // nodes per round (4 waves x 16)
#define XB 264                // x row stride (ushorts): 528B, 16B-mult, %32w==4 -> conflict-free b128
#define UB 264                // U_t row stride (ushorts)
#define EP 40                 // e_t row stride (ushorts): 80B

typedef __attribute__((ext_vector_type(8))) short short8;    // bf16x8 MFMA operand
typedef __attribute__((ext_vector_type(4))) float floatx4;   // f32x4 MFMA accum

// f32 -> bf16 (RNE) top-16
__device__ __forceinline__ unsigned int f2b(float f) {
    unsigned int u = __float_as_uint(f);
    return (u + 0x7fffu + ((u >> 16) & 1u)) >> 16;
}

// ---------------- graph start offsets: gstart[g] = lower_bound(batch, g) ----
__global__ void k_gstart(const int* __restrict__ batch, int N, int G,
                         int* __restrict__ gstart) {
    int g = threadIdx.x;
    if (g > G) return;
    if (g == 0) { gstart[0] = 0; return; }
    if (g == G) { gstart[G] = N; return; }
    int lo = 0, hi = N;
    while (lo < hi) {
        int mid = (lo + hi) >> 1;
        if (batch[mid] < g) lo = mid + 1; else hi = mid;
    }
    gstart[g] = lo;
}

// ---------------- per-star precompute: q, U_t(bf16), self score -------------
__global__ void k_star_prep(const float* __restrict__ stars,
                            const float* __restrict__ Wq_w, const float* __restrict__ Wq_b,
                            const float* __restrict__ Wk_w, const float* __restrict__ Wk_b,
                            unsigned short* __restrict__ U16, float* __restrict__ eself,
                            float* __restrict__ denom) {
    __shared__ float xs[C];
    __shared__ float qv[C];
    __shared__ float kv[C];
    const int gs = blockIdx.x;           // g*4 + s
    const int g = gs >> 2, s = gs & 3;
    const int t = threadIdx.x;

    xs[t] = stars[gs * C + t];
    __syncthreads();

    float aq = Wq_b[t], ak = Wk_b[t];
    const float* wq = Wq_w + (size_t)t * C;
    const float* wk = Wk_w + (size_t)t * C;
    #pragma unroll 4
    for (int j = 0; j < C; j += 4) {
        float4 x4 = *(const float4*)(xs + j);
        float4 a4 = *(const float4*)(wq + j);
        aq += a4.x * x4.x + a4.y * x4.y + a4.z * x4.z + a4.w * x4.w;
        float4 b4 = *(const float4*)(wk + j);
        ak += b4.x * x4.x + b4.y * x4.y + b4.z * x4.z + b4.w * x4.w;
    }
    qv[t] = aq; kv[t] = ak;
    __syncthreads();

    {   // self score per head
        float p = qv[t] * kv[t];
        #pragma unroll
        for (int off = 16; off; off >>= 1) p += __shfl_down(p, off, 32);
        if ((t & 31) == 0) {
            int h = t >> 5;
            float e = __expf(p * RSQRT_DH);
            eself[g * SLOTS + s * HEADS + h] = e;
            denom[g * SLOTS + s * HEADS + h] = e;   // init with self term
        }
    }

    // U_t bf16: U16[g][slot=s*8+h][c] = bf16( (1/sqrt(dh)) * sum_d Wk[h*32+d][c]*q[h*32+d] )
    {
        const int c = t;
        #pragma unroll
        for (int h = 0; h < HEADS; ++h) {
            float u = 0.f;
            for (int d = 0; d < 32; ++d)
                u += Wk_w[(size_t)(h * 32 + d) * C + c] * qv[h * 32 + d];
            U16[((size_t)g * SLOTS + s * HEADS + h) * C + c] =
                (unsigned short)f2b(u * RSQRT_DH);
        }
    }
}

// ---------------- fused MFMA kernel: QK^T + exp + denom + PV ----------------
// block: 4 waves. Wave w owns node chunk of 16 per round (scores);
// then switches to c-slice [w*64, w*64+64) for PV over all 4 chunks.
__global__ __launch_bounds__(256, 2)
void k_fused(const float* __restrict__ nodes, const unsigned short* __restrict__ U16,
             const int* __restrict__ gstart, float* __restrict__ denom,
             float* __restrict__ Ypart) {
    __shared__ unsigned short u_lds[SLOTS * UB];       // 16,896 B  U_t [s][c]
    __shared__ unsigned short x_lds[4 * CWK * XB];     // 33,792 B  x  [chunk][n][c] bf16
    __shared__ unsigned short e_lds[2 * SLOTS * EP];   //  5,120 B  e_t[pair][s][n] bf16

    const int g = blockIdx.x / PF, pb = blockIdx.x % PF;
    const int t = threadIdx.x;
    const int wv = t >> 6;        // wave 0..3
    const int l  = t & 63;
    const int lr = l & 15;        // 16-lane index
    const int q  = l >> 4;        // quad 0..3

    const int glo = gstart[g], ghi = gstart[g + 1];
    const int len = ghi - glo;
    const int L = (len + PF - 1) / PF;
    const int lo = glo + pb * L;
    const int hi = min(lo + L, ghi);
    const int nr = (hi > lo) ? (hi - lo + RND - 1) / RND : 0;

    // ---- stage U_t (one-time): wave w stages rows w*8 .. w*8+7 ----
    {
        const unsigned short* ug = U16 + (size_t)g * SLOTS * C;
        #pragma unroll
        for (int i = 0; i < 8; ++i) {
            int r = wv * 8 + i;
            *(uint2*)&u_lds[r * UB + l * 4] = *(const uint2*)&ug[r * C + l * 4];
        }
    }

    const floatx4 z4 = {0.f, 0.f, 0.f, 0.f};
    floatx4 yacc[2][4];           // [st][ct] : Y[s=st*16+q*4+r][c=wv*64+ct*16+lr]
    #pragma unroll
    for (int a = 0; a < 2; ++a)
        #pragma unroll
        for (int b = 0; b < 4; ++b) yacc[a][b] = z4;
    float dsum[8];                // per-lane partial denom (s = mt*16+q*4+r, n = lr)
    #pragma unroll
    for (int i = 0; i < 8; ++i) dsum[i] = 0.f;

    unsigned short* xw = &x_lds[wv * CWK * XB];

    // prefetch round 0 into registers
    float4 xr[CWK];
    if (nr > 0) {
        int base = lo + wv * CWK;
        #pragma unroll
        for (int i = 0; i < CWK; ++i) {
            int gn = base + i;
            xr[i] = (gn < hi) ? *(const float4*)&nodes[(size_t)gn * C + l * 4]
                              : make_float4(0.f, 0.f, 0.f, 0.f);
        }
    }

    for (int rd = 0; rd < nr; ++rd) {
        __syncthreads();          // prev PV done (round>0); U_t staged (round 0)

        // ---- write own chunk to LDS (bf16) ----
        #pragma unroll
        for (int i = 0; i < CWK; ++i) {
            uint2 w;
            w.x = f2b(xr[i].x) | (f2b(xr[i].y) << 16);
            w.y = f2b(xr[i].z) | (f2b(xr[i].w) << 16);
            *(uint2*)&xw[i * XB + l * 4] = w;
        }
        // ---- prefetch next round (in flight during QK^T + PV) ----
        if (rd + 1 < nr) {
            int base = lo + (rd + 1) * RND + wv * CWK;
            #pragma unroll
            for (int i = 0; i < CWK; ++i) {
                int gn = base + i;
                xr[i] = (gn < hi) ? *(const float4*)&nodes[(size_t)gn * C + l * 4]
                                  : make_float4(0.f, 0.f, 0.f, 0.f);
            }
        }

        // ---- QK^T on own chunk (no barrier needed: same-wave LDS deps) ----
        // S_T[s][n] tiles mt=0,1 ; A = U_t rows, B = x rows, K = 256
        floatx4 sacc0 = z4, sacc1 = z4;
        {
            const unsigned short* ur0 = &u_lds[lr * UB + q * 8];
            const unsigned short* ur1 = &u_lds[(16 + lr) * UB + q * 8];
            const unsigned short* xrw = &xw[lr * XB + q * 8];
            #pragma unroll
            for (int kt = 0; kt < 8; ++kt) {
                short8 a0 = *(const short8*)(ur0 + kt * 32);
                short8 a1 = *(const short8*)(ur1 + kt * 32);
                short8 bx = *(const short8*)(xrw + kt * 32);
                sacc0 = __builtin_amdgcn_mfma_f32_16x16x32_bf16(a0, bx, sacc0, 0, 0, 0);
                sacc1 = __builtin_amdgcn_mfma_f32_16x16x32_bf16(a1, bx, sacc1, 0, 0, 0);
            }
        }

        // ---- exp, mask invalid nodes, accumulate denom, write e_t ----
        {
            int base = lo + rd * RND + wv * CWK;
            const bool valid = (base + lr) < hi;      // this lane's node n = lr
            unsigned short* ew = &e_lds[(wv >> 1) * SLOTS * EP + (wv & 1) * 16 + lr];
            #pragma unroll
            for (int r = 0; r < 4; ++r) {
                float e0 = valid ? __expf(sacc0[r]) : 0.f;
                float e1 = valid ? __expf(sacc1[r]) : 0.f;
                dsum[r]     += e0;
                dsum[4 + r] += e1;
                ew[(q * 4 + r) * EP]        = (unsigned short)f2b(e0);
                ew[(16 + q * 4 + r) * EP]   = (unsigned short)f2b(e1);
            }
        }
        __syncthreads();          // all e_t + all x chunks ready

        // ---- PV: Y[s][c-slice] += e_t[pair] * x[pair]  (K=32 per pair) ----
        #pragma unroll
        for (int p = 0; p < 2; ++p) {
            short8 pa0 = *(const short8*)&e_lds[(p * SLOTS + lr) * EP + q * 8];
            short8 pa1 = *(const short8*)&e_lds[(p * SLOTS + 16 + lr) * EP + q * 8];
            const unsigned short* xb0 =
                &x_lds[((p * 2 + (q >> 1)) * CWK + (q & 1) * 8) * XB + wv * 64 + lr];
            #pragma unroll
            for (int ct = 0; ct < 4; ++ct) {
                short8 bx;
                #pragma unroll
                for (int j = 0; j < 8; ++j) bx[j] = (short)xb0[j * XB + ct * 16];
                yacc[0][ct] = __builtin_amdgcn_mfma_f32_16x16x32_bf16(pa0, bx, yacc[0][ct], 0, 0, 0);
                yacc[1][ct] = __builtin_amdgcn_mfma_f32_16x16x32_bf16(pa1, bx, yacc[1][ct], 0, 0, 0);
            }
        }
    }

    // ---- flush Y partials (plain stores; every block writes its full slice) ----
    {
        float* yg = &Ypart[(((size_t)g * PF + pb) * SLOTS) * C];
        #pragma unroll
        for (int st = 0; st < 2; ++st)
            #pragma unroll
            for (int ct = 0; ct < 4; ++ct)
                #pragma unroll
                for (int r = 0; r < 4; ++r)
                    yg[(st * 16 + q * 4 + r) * C + wv * 64 + ct * 16 + lr] = yacc[st][ct][r];
    }

    // ---- flush denom: reduce over the 16 lanes of each quad (n-direction) ----
    #pragma unroll
    for (int i = 0; i < 8; ++i) {
        float v = dsum[i];
        v += __shfl_xor(v, 1);
        v += __shfl_xor(v, 2);
        v += __shfl_xor(v, 4);
        v += __shfl_xor(v, 8);
        dsum[i] = v;
    }
    if (lr == 0) {
        #pragma unroll
        for (int mt = 0; mt < 2; ++mt)
            #pragma unroll
            for (int r = 0; r < 4; ++r)
                atomicAdd(&denom[g * SLOTS + mt * 16 + q * 4 + r], dsum[mt * 4 + r]);
    }
}

// ---------------- epilogue: out = LN(elu(Wv*(Ysum/denom + cself*x) + bv) + stars)
__global__ void k_epilogue(const float* __restrict__ stars,
                           const float* __restrict__ Wv_w, const float* __restrict__ Wv_b,
                           const float* __restrict__ gamma, const float* __restrict__ beta,
                           const float* __restrict__ Ypart, const float* __restrict__ eself,
                           const float* __restrict__ denom, float* __restrict__ out) {
    __shared__ float xs[C];
    __shared__ float yl[HEADS * C];
    __shared__ float cs[HEADS], ivd[HEADS], scl[HEADS];
    __shared__ float rb[8];

    const int gs = blockIdx.x;
    const int g = gs >> 2, s = gs & 3;
    const int t = threadIdx.x;

    xs[t] = stars[gs * C + t];
    if (t < HEADS) {
        float dn = denom[g * SLOTS + s * HEADS + t];
        float iv = 1.f / (dn + 1e-16f);
        ivd[t] = iv;
        cs[t] = eself[g * SLOTS + s * HEADS + t] * iv;
        scl[t] = dn * iv;
    }
    __syncthreads();

    // sum partials over pb, normalize, add self contribution
    for (int i = t; i < HEADS * C; i += 256) {
        int h = i >> 8, j = i & 255;
        float sum = 0.f;
        #pragma unroll
        for (int pbi = 0; pbi < PF; ++pbi)
            sum += Ypart[(((size_t)g * PF + pbi) * SLOTS + s * HEADS + h) * C + j];
        yl[i] = sum * ivd[h] + cs[h] * xs[j];
    }
    __syncthreads();

    const int c = t, h = c >> 5;
    float a = 0.f;
    const float* wv = Wv_w + (size_t)c * C;
    const float* yh = &yl[h * C];
    #pragma unroll 4
    for (int j = 0; j < C; j += 4) {
        float4 w4 = *(const float4*)(wv + j);
        float4 y4 = *(const float4*)(yh + j);
        a += w4.x * y4.x + w4.y * y4.y + w4.z * y4.z + w4.w * y4.w;
    }
    a += Wv_b[c] * scl[h];

    float v = a > 0.f ? a : (__expf(a) - 1.f);     // ELU
    float r = v + xs[c];                            // residual

    float ssum = r;
    #pragma unroll
    for (int off = 32; off; off >>= 1) ssum += __shfl_down(ssum, off, 64);
    const int wid = t >> 6, lane = t & 63;
    if (lane == 0) rb[wid] = ssum;
    __syncthreads();
    const float mu = (rb[0] + rb[1] + rb[2] + rb[3]) * (1.f / 256.f);
    const float d = r - mu;
    float vsum = d * d;
    #pragma unroll
    for (int off = 32; off; off >>= 1) vsum += __shfl_down(vsum, off, 64);
    if (lane == 0) rb[4 + wid] = vsum;
    __syncthreads();
    const float var = (rb[4] + rb[5] + rb[6] + rb[7]) * (1.f / 256.f);
    out[gs * C + c] = d * rsqrtf(var + LN_EPS) * gamma[c] + beta[c];
}

// ---------------------------------------------------------------------------
extern "C" void kernel_launch(void* const* d_in, const int* in_sizes, int n_in,
                              void* d_out, int out_size, void* d_ws, size_t ws_size,
                              hipStream_t stream) {
    const float* stars = (const float*)d_in[0];
    const float* nodes = (const float*)d_in[1];
    const int*   batch = (const int*)d_in[2];
    const float* Wq_w  = (const float*)d_in[3];
    const float* Wq_b  = (const float*)d_in[4];
    const float* Wk_w  = (const float*)d_in[5];
    const float* Wk_b  = (const float*)d_in[6];
    const float* Wv_w  = (const float*)d_in[7];
    const float* Wv_b  = (const float*)d_in[8];
    const float* gamma = (const float*)d_in[9];
    const float* beta  = (const float*)d_in[10];

    const int N = in_sizes[1] / C;
    const int G = in_sizes[0] / (NUM_STAR * C);

    unsigned short* U16 = (unsigned short*)d_ws;                    // G*SLOTS*C ush
    float* eself = (float*)((char*)d_ws + (size_t)G * SLOTS * C * 2);
    float* denom = eself + (size_t)G * SLOTS;
    float* Ypart = denom + (size_t)G * SLOTS;                       // G*PF*SLOTS*C f32
    int*   gstart = (int*)(Ypart + (size_t)G * PF * SLOTS * C);     // G+1

    float* out = (float*)d_out;

    k_gstart<<<1, 64, 0, stream>>>(batch, N, G, gstart);
    k_star_prep<<<G * NUM_STAR, 256, 0, stream>>>(stars, Wq_w, Wq_b, Wk_w, Wk_b,
                                                  U16, eself, denom);
    k_fused<<<G * PF, 256, 0, stream>>>(nodes, U16, gstart, denom, Ypart);
    k_epilogue<<<G * NUM_STAR, 256, 0, stream>>>(stars, Wv_w, Wv_b, gamma, beta,
                                                 Ypart, eself, denom, out);
}

// Round 5
// 73.038 us; speedup vs baseline: 3.9571x; 1.0086x over previous
//
#include <hip/hip_runtime.h>
#include <math.h>

#define HEADS 8
#define C 256
#define NUM_STAR 4
#define SLOTS 32              // NUM_STAR * HEADS
#define RSQRT_DH 0.17677669529663688f   // 1/sqrt(32)
#define LN_EPS 1e-5f
#define PF 16                 // fused-kernel partitions per graph (grid = G*PF = 512)
#define CWK 16                // nodes per wave chunk
#define RND 64                // nodes per round (4 waves x 16)
#define XB 264                // x_nc row stride (ushorts): 528B; QK^T b128 reads conflict-free
#define ST 40                 // x_cn row stride (ushorts): 32 nodes + 8 pad; 16B-aligned rows
#define CNP (C * ST)          // x_cn per-pair size (ushorts) = 10240
#define EP 40                 // e_t row stride (ushorts)

typedef __attribute__((ext_vector_type(8))) short short8;    // bf16x8 MFMA operand
typedef __attribute__((ext_vector_type(4))) float floatx4;   // f32x4 MFMA accum

// f32 -> bf16 (RNE) top-16
__device__ __forceinline__ unsigned int f2b(float f) {
    unsigned int u = __float_as_uint(f);
    return (u + 0x7fffu + ((u >> 16) & 1u)) >> 16;
}
__device__ __forceinline__ float fcomp(const float4& v, int jj) {
    return jj == 0 ? v.x : jj == 1 ? v.y : jj == 2 ? v.z : v.w;
}

// ---------------- star prep (+ gstart fold in last block) -------------------
__global__ void k_star_prep(const float* __restrict__ stars,
                            const float* __restrict__ Wq_w, const float* __restrict__ Wq_b,
                            const float* __restrict__ Wk_w, const float* __restrict__ Wk_b,
                            unsigned short* __restrict__ U16, float* __restrict__ eself,
                            float* __restrict__ denom,
                            const int* __restrict__ batch, int N, int G,
                            int* __restrict__ gstart) {
    if (blockIdx.x == gridDim.x - 1) {       // gstart block
        int g = threadIdx.x;
        if (g > G) return;
        if (g == 0) { gstart[0] = 0; return; }
        if (g == G) { gstart[G] = N; return; }
        int lo = 0, hi = N;
        while (lo < hi) {
            int mid = (lo + hi) >> 1;
            if (batch[mid] < g) lo = mid + 1; else hi = mid;
        }
        gstart[g] = lo;
        return;
    }

    __shared__ float xs[C];
    __shared__ float qv[C];
    __shared__ float kv[C];
    const int gs = blockIdx.x;           // g*4 + s
    const int g = gs >> 2, s = gs & 3;
    const int t = threadIdx.x;

    xs[t] = stars[gs * C + t];
    __syncthreads();

    float aq = Wq_b[t], ak = Wk_b[t];
    const float* wq = Wq_w + (size_t)t * C;
    const float* wk = Wk_w + (size_t)t * C;
    #pragma unroll 4
    for (int j = 0; j < C; j += 4) {
        float4 x4 = *(const float4*)(xs + j);
        float4 a4 = *(const float4*)(wq + j);
        aq += a4.x * x4.x + a4.y * x4.y + a4.z * x4.z + a4.w * x4.w;
        float4 b4 = *(const float4*)(wk + j);
        ak += b4.x * x4.x + b4.y * x4.y + b4.z * x4.z + b4.w * x4.w;
    }
    qv[t] = aq; kv[t] = ak;
    __syncthreads();

    {   // self score per head
        float p = qv[t] * kv[t];
        #pragma unroll
        for (int off = 16; off; off >>= 1) p += __shfl_down(p, off, 32);
        if ((t & 31) == 0) {
            int h = t >> 5;
            float e = __expf(p * RSQRT_DH);
            eself[g * SLOTS + s * HEADS + h] = e;
            denom[g * SLOTS + s * HEADS + h] = e;   // init with self term
        }
    }

    // U_t bf16: U16[g][slot=s*8+h][c]
    {
        const int c = t;
        #pragma unroll
        for (int h = 0; h < HEADS; ++h) {
            float u = 0.f;
            for (int d = 0; d < 32; ++d)
                u += Wk_w[(size_t)(h * 32 + d) * C + c] * qv[h * 32 + d];
            U16[((size_t)g * SLOTS + s * HEADS + h) * C + c] =
                (unsigned short)f2b(u * RSQRT_DH);
        }
    }
}

// ---------------- fused MFMA kernel: QK^T + exp + denom + PV ----------------
__global__ __launch_bounds__(256, 2)
void k_fused(const float* __restrict__ nodes, const unsigned short* __restrict__ U16,
             const int* __restrict__ gstart, float* __restrict__ denom,
             float* __restrict__ Ypart) {
    __shared__ unsigned short x_nc[4 * CWK * XB];   // 33,792 B  [chunk][n][c]
    __shared__ unsigned short x_cn[2 * CNP];        // 40,960 B  [pair][c][n] swizzled
    __shared__ unsigned short e_lds[2 * SLOTS * EP];//  5,120 B  [pair][s][n]

    const int g = blockIdx.x / PF, pb = blockIdx.x % PF;
    const int t = threadIdx.x;
    const int wv = t >> 6;        // wave 0..3
    const int l  = t & 63;
    const int lr = l & 15;
    const int q  = l >> 4;

    const int glo = gstart[g], ghi = gstart[g + 1];
    const int len = ghi - glo;
    const int L = (len + PF - 1) / PF;
    const int lo = glo + pb * L;
    const int hi = min(lo + L, ghi);
    const int nr = (hi > lo) ? (hi - lo + RND - 1) / RND : 0;

    // ---- U_t fragments in registers (A-operand, both 16-row tiles) ----
    short8 ureg[2][8];
    {
        const unsigned short* ug = U16 + (size_t)g * SLOTS * C;
        #pragma unroll
        for (int st2 = 0; st2 < 2; ++st2)
            #pragma unroll
            for (int kt = 0; kt < 8; ++kt)
                ureg[st2][kt] = *(const short8*)&ug[(st2 * 16 + lr) * C + q * 8 + kt * 32];
    }

    const floatx4 z4 = {0.f, 0.f, 0.f, 0.f};
    floatx4 yacc[2][4];           // [st][ct]: Y[s=st*16+q*4+r][c=wv*64+ct*16+lr]
    #pragma unroll
    for (int a = 0; a < 2; ++a)
        #pragma unroll
        for (int b = 0; b < 4; ++b) yacc[a][b] = z4;
    float dsum[8];
    #pragma unroll
    for (int i = 0; i < 8; ++i) dsum[i] = 0.f;

    unsigned short* xw = &x_nc[wv * CWK * XB];
    const int p_own = wv >> 1, hw = wv & 1;

    // prefetch round 0
    float4 xr[CWK];
    if (nr > 0) {
        int base = lo + wv * CWK;
        #pragma unroll
        for (int i = 0; i < CWK; ++i) {
            int gn = base + i;
            xr[i] = (gn < hi) ? *(const float4*)&nodes[(size_t)gn * C + l * 4]
                              : make_float4(0.f, 0.f, 0.f, 0.f);
        }
    }

    for (int rd = 0; rd < nr; ++rd) {
        __syncthreads();          // prev PV done reading x/e

        // ---- write x_nc (node-major) ----
        #pragma unroll
        for (int i = 0; i < CWK; ++i) {
            uint2 w2;
            w2.x = f2b(xr[i].x) | (f2b(xr[i].y) << 16);
            w2.y = f2b(xr[i].z) | (f2b(xr[i].w) << 16);
            *(uint2*)&xw[i * XB + l * 4] = w2;
        }
        // ---- write x_cn (channel-major, 8-node blocks XOR-swizzled) ----
        #pragma unroll
        for (int jj = 0; jj < 4; ++jj) {
            const int c = 4 * l + jj;
            const int sz = ((c >> 2) ^ (c >> 4)) & 3;
            uint4 ulo, uhi;
            ulo.x = f2b(fcomp(xr[0], jj)) | (f2b(fcomp(xr[1], jj)) << 16);
            ulo.y = f2b(fcomp(xr[2], jj)) | (f2b(fcomp(xr[3], jj)) << 16);
            ulo.z = f2b(fcomp(xr[4], jj)) | (f2b(fcomp(xr[5], jj)) << 16);
            ulo.w = f2b(fcomp(xr[6], jj)) | (f2b(fcomp(xr[7], jj)) << 16);
            uhi.x = f2b(fcomp(xr[8], jj)) | (f2b(fcomp(xr[9], jj)) << 16);
            uhi.y = f2b(fcomp(xr[10], jj)) | (f2b(fcomp(xr[11], jj)) << 16);
            uhi.z = f2b(fcomp(xr[12], jj)) | (f2b(fcomp(xr[13], jj)) << 16);
            uhi.w = f2b(fcomp(xr[14], jj)) | (f2b(fcomp(xr[15], jj)) << 16);
            unsigned short* basep = &x_cn[p_own * CNP + c * ST];
            *(uint4*)&basep[((hw * 2 + 0) ^ sz) * 8] = ulo;   // nodes hw*16+0..7
            *(uint4*)&basep[((hw * 2 + 1) ^ sz) * 8] = uhi;   // nodes hw*16+8..15
        }
        // ---- prefetch next round (in flight during QK^T + PV) ----
        if (rd + 1 < nr) {
            int base = lo + (rd + 1) * RND + wv * CWK;
            #pragma unroll
            for (int i = 0; i < CWK; ++i) {
                int gn = base + i;
                xr[i] = (gn < hi) ? *(const float4*)&nodes[(size_t)gn * C + l * 4]
                                  : make_float4(0.f, 0.f, 0.f, 0.f);
            }
        }

        // ---- QK^T on own chunk (same-wave LDS dep, no barrier needed) ----
        floatx4 sacc0 = z4, sacc1 = z4;
        {
            const unsigned short* xrw = &xw[lr * XB + q * 8];
            #pragma unroll
            for (int kt = 0; kt < 8; ++kt) {
                short8 bx = *(const short8*)(xrw + kt * 32);
                sacc0 = __builtin_amdgcn_mfma_f32_16x16x32_bf16(ureg[0][kt], bx, sacc0, 0, 0, 0);
                sacc1 = __builtin_amdgcn_mfma_f32_16x16x32_bf16(ureg[1][kt], bx, sacc1, 0, 0, 0);
            }
        }

        // ---- exp, mask, denom, e_t write ----
        {
            int base = lo + rd * RND + wv * CWK;
            const bool valid = (base + lr) < hi;
            unsigned short* ew = &e_lds[p_own * SLOTS * EP + hw * 16 + lr];
            #pragma unroll
            for (int r = 0; r < 4; ++r) {
                float e0 = valid ? __expf(sacc0[r]) : 0.f;
                float e1 = valid ? __expf(sacc1[r]) : 0.f;
                dsum[r]     += e0;
                dsum[4 + r] += e1;
                ew[(q * 4 + r) * EP]      = (unsigned short)f2b(e0);
                ew[(16 + q * 4 + r) * EP] = (unsigned short)f2b(e1);
            }
        }
        __syncthreads();          // all e_t + x_cn ready

        // ---- PV: Y[s][c-slice] += e_t[p] * x[p]  (K=32 per pair) ----
        #pragma unroll
        for (int p = 0; p < 2; ++p) {
            short8 pa0 = *(const short8*)&e_lds[(p * SLOTS + lr) * EP + q * 8];
            short8 pa1 = *(const short8*)&e_lds[(p * SLOTS + 16 + lr) * EP + q * 8];
            #pragma unroll
            for (int ct = 0; ct < 4; ++ct) {
                const int c = wv * 64 + ct * 16 + lr;
                const int sz = ((c >> 2) ^ (c >> 4)) & 3;
                short8 bx = *(const short8*)&x_cn[p * CNP + c * ST + ((q ^ sz) * 8)];
                yacc[0][ct] = __builtin_amdgcn_mfma_f32_16x16x32_bf16(pa0, bx, yacc[0][ct], 0, 0, 0);
                yacc[1][ct] = __builtin_amdgcn_mfma_f32_16x16x32_bf16(pa1, bx, yacc[1][ct], 0, 0, 0);
            }
        }
    }

    // ---- flush Y partials (also zero-fills when nr==0) ----
    {
        float* yg = &Ypart[(((size_t)g * PF + pb) * SLOTS) * C];
        #pragma unroll
        for (int st = 0; st < 2; ++st)
            #pragma unroll
            for (int ct = 0; ct < 4; ++ct)
                #pragma unroll
                for (int r = 0; r < 4; ++r)
                    yg[(st * 16 + q * 4 + r) * C + wv * 64 + ct * 16 + lr] = yacc[st][ct][r];
    }

    // ---- denom: reduce over 16 lanes (n-direction), atomics from lr==0 ----
    #pragma unroll
    for (int i = 0; i < 8; ++i) {
        float v = dsum[i];
        v += __shfl_xor(v, 1);
        v += __shfl_xor(v, 2);
        v += __shfl_xor(v, 4);
        v += __shfl_xor(v, 8);
        dsum[i] = v;
    }
    if (lr == 0 && nr > 0) {
        #pragma unroll
        for (int mt = 0; mt < 2; ++mt)
            #pragma unroll
            for (int r = 0; r < 4; ++r)
                atomicAdd(&denom[g * SLOTS + mt * 16 + q * 4 + r], dsum[mt * 4 + r]);
    }
}

// ---------------- epilogue: out = LN(elu(Wv*(Ysum/denom + cself*x) + bv) + stars)
__global__ void k_epilogue(const float* __restrict__ stars,
                           const float* __restrict__ Wv_w, const float* __restrict__ Wv_b,
                           const float* __restrict__ gamma, const float* __restrict__ beta,
                           const float* __restrict__ Ypart, const float* __restrict__ eself,
                           const float* __restrict__ denom, float* __restrict__ out) {
    __shared__ float xs[C];
    __shared__ float yl[HEADS * C];
    __shared__ float cs[HEADS], ivd[HEADS], scl[HEADS];
    __shared__ float rb[8];

    const int gs = blockIdx.x;
    const int g = gs >> 2, s = gs & 3;
    const int t = threadIdx.x;

    xs[t] = stars[gs * C + t];
    if (t < HEADS) {
        float dn = denom[g * SLOTS + s * HEADS + t];
        float iv = 1.f / (dn + 1e-16f);
        ivd[t] = iv;
        cs[t] = eself[g * SLOTS + s * HEADS + t] * iv;
        scl[t] = dn * iv;
    }
    __syncthreads();

    for (int i = t; i < HEADS * C; i += 256) {
        int h = i >> 8, j = i & 255;
        float sum = 0.f;
        #pragma unroll
        for (int pbi = 0; pbi < PF; ++pbi)
            sum += Ypart[(((size_t)g * PF + pbi) * SLOTS + s * HEADS + h) * C + j];
        yl[i] = sum * ivd[h] + cs[h] * xs[j];
    }
    __syncthreads();

    const int c = t, h = c >> 5;
    float a = 0.f;
    const float* wv = Wv_w + (size_t)c * C;
    const float* yh = &yl[h * C];
    #pragma unroll 4
    for (int j = 0; j < C; j += 4) {
        float4 w4 = *(const float4*)(wv + j);
        float4 y4 = *(const float4*)(yh + j);
        a += w4.x * y4.x + w4.y * y4.y + w4.z * y4.z + w4.w * y4.w;
    }
    a += Wv_b[c] * scl[h];

    float v = a > 0.f ? a : (__expf(a) - 1.f);     // ELU
    float r = v + xs[c];                            // residual

    float ssum = r;
    #pragma unroll
    for (int off = 32; off; off >>= 1) ssum += __shfl_down(ssum, off, 64);
    const int wid = t >> 6, lane = t & 63;
    if (lane == 0) rb[wid] = ssum;
    __syncthreads();
    const float mu = (rb[0] + rb[1] + rb[2] + rb[3]) * (1.f / 256.f);
    const float d = r - mu;
    float vsum = d * d;
    #pragma unroll
    for (int off = 32; off; off >>= 1) vsum += __shfl_down(vsum, off, 64);
    if (lane == 0) rb[4 + wid] = vsum;
    __syncthreads();
    const float var = (rb[4] + rb[5] + rb[6] + rb[7]) * (1.f / 256.f);
    out[gs * C + c] = d * rsqrtf(var + LN_EPS) * gamma[c] + beta[c];
}

// ---------------------------------------------------------------------------
extern "C" void kernel_launch(void* const* d_in, const int* in_sizes, int n_in,
                              void* d_out, int out_size, void* d_ws, size_t ws_size,
                              hipStream_t stream) {
    const float* stars = (const float*)d_in[0];
    const float* nodes = (const float*)d_in[1];
    const int*   batch = (const int*)d_in[2];
    const float* Wq_w  = (const float*)d_in[3];
    const float* Wq_b  = (const float*)d_in[4];
    const float* Wk_w  = (const float*)d_in[5];
    const float* Wk_b  = (const float*)d_in[6];
    const float* Wv_w  = (const float*)d_in[7];
    const float* Wv_b  = (const float*)d_in[8];
    const float* gamma = (const float*)d_in[9];
    const float* beta  = (const float*)d_in[10];

    const int N = in_sizes[1] / C;
    const int G = in_sizes[0] / (NUM_STAR * C);

    unsigned short* U16 = (unsigned short*)d_ws;                    // G*SLOTS*C ush
    float* eself = (float*)((char*)d_ws + (size_t)G * SLOTS * C * 2);
    float* denom = eself + (size_t)G * SLOTS;
    float* Ypart = denom + (size_t)G * SLOTS;                       // G*PF*SLOTS*C f32
    int*   gstart = (int*)(Ypart + (size_t)G * PF * SLOTS * C);     // G+1

    float* out = (float*)d_out;

    k_star_prep<<<G * NUM_STAR + 1, 256, 0, stream>>>(stars, Wq_w, Wq_b, Wk_w, Wk_b,
                                                      U16, eself, denom,
                                                      batch, N, G, gstart);
    k_fused<<<G * PF, 256, 0, stream>>>(nodes, U16, gstart, denom, Ypart);
    k_epilogue<<<G * NUM_STAR, 256, 0, stream>>>(stars, Wv_w, Wv_b, gamma, beta,
                                                 Ypart, eself, denom, out);
}

// Round 6
// 70.653 us; speedup vs baseline: 4.0907x; 1.0338x over previous
//
#include <hip/hip_runtime.h>
#include <math.h>

#define HEADS 8
#define C 256
#define NUM_STAR 4
#define SLOTS 32              // NUM_STAR * HEADS
#define RSQRT_DH 0.17677669529663688f   // 1/sqrt(32)
#define LN_EPS 1e-5f
#define PF 16                 // fused-kernel partitions per graph (grid = G*PF = 512)
#define CWK 16                // nodes per wave chunk
#define RND 64                // nodes per round (4 waves x 16)
#define XB 264                // x_nc row stride (ushorts): 528B; QK^T b128 reads conflict-free
#define ST 40                 // x_cn row stride (ushorts): 32 nodes + 8 pad; 16B-aligned rows
#define CNP (C * ST)          // x_cn per-pair size (ushorts) = 10240
#define EP 40                 // e_t row stride (ushorts)

typedef __attribute__((ext_vector_type(8))) short short8;    // bf16x8 MFMA operand
typedef __attribute__((ext_vector_type(4))) float floatx4;   // f32x4 MFMA accum

// f32 -> bf16 (RNE) top-16 (scalar)
__device__ __forceinline__ unsigned int f2b(float f) {
    unsigned int u = __float_as_uint(f);
    return (u + 0x7fffu + ((u >> 16) & 1u)) >> 16;
}
// packed f32x2 -> bf16x2 (RNE), lo -> [15:0], hi -> [31:16]
__device__ __forceinline__ unsigned int pk_bf16(float lo, float hi) {
    unsigned int r;
    asm("v_cvt_pk_bf16_f32 %0, %1, %2" : "=v"(r) : "v"(lo), "v"(hi));
    return r;
}
__device__ __forceinline__ float fcomp(const float4& v, int jj) {
    return jj == 0 ? v.x : jj == 1 ? v.y : jj == 2 ? v.z : v.w;
}

// raw barrier: LDS-visible, but does NOT drain vmcnt (prefetch stays in flight)
__device__ __forceinline__ void block_sync_lds() {
    asm volatile("s_waitcnt lgkmcnt(0)" ::: "memory");
    __builtin_amdgcn_sched_barrier(0);
    __builtin_amdgcn_s_barrier();
    __builtin_amdgcn_sched_barrier(0);
}

// ---------------- star prep (+ gstart fold in last block) -------------------
__global__ void k_star_prep(const float* __restrict__ stars,
                            const float* __restrict__ Wq_w, const float* __restrict__ Wq_b,
                            const float* __restrict__ Wk_w, const float* __restrict__ Wk_b,
                            unsigned short* __restrict__ U16, float* __restrict__ eself,
                            float* __restrict__ denom,
                            const int* __restrict__ batch, int N, int G,
                            int* __restrict__ gstart) {
    if (blockIdx.x == gridDim.x - 1) {       // gstart block
        int g = threadIdx.x;
        if (g > G) return;
        if (g == 0) { gstart[0] = 0; return; }
        if (g == G) { gstart[G] = N; return; }
        int lo = 0, hi = N;
        while (lo < hi) {
            int mid = (lo + hi) >> 1;
            if (batch[mid] < g) lo = mid + 1; else hi = mid;
        }
        gstart[g] = lo;
        return;
    }

    __shared__ float xs[C];
    __shared__ float qv[C];
    __shared__ float kv[C];
    const int gs = blockIdx.x;           // g*4 + s
    const int g = gs >> 2, s = gs & 3;
    const int t = threadIdx.x;

    xs[t] = stars[gs * C + t];
    __syncthreads();

    float aq = Wq_b[t], ak = Wk_b[t];
    const float* wq = Wq_w + (size_t)t * C;
    const float* wk = Wk_w + (size_t)t * C;
    #pragma unroll 4
    for (int j = 0; j < C; j += 4) {
        float4 x4 = *(const float4*)(xs + j);
        float4 a4 = *(const float4*)(wq + j);
        aq += a4.x * x4.x + a4.y * x4.y + a4.z * x4.z + a4.w * x4.w;
        float4 b4 = *(const float4*)(wk + j);
        ak += b4.x * x4.x + b4.y * x4.y + b4.z * x4.z + b4.w * x4.w;
    }
    qv[t] = aq; kv[t] = ak;
    __syncthreads();

    {   // self score per head
        float p = qv[t] * kv[t];
        #pragma unroll
        for (int off = 16; off; off >>= 1) p += __shfl_down(p, off, 32);
        if ((t & 31) == 0) {
            int h = t >> 5;
            float e = __expf(p * RSQRT_DH);
            eself[g * SLOTS + s * HEADS + h] = e;
            denom[g * SLOTS + s * HEADS + h] = e;   // init with self term
        }
    }

    // U_t bf16: U16[g][slot=s*8+h][c]
    {
        const int c = t;
        #pragma unroll
        for (int h = 0; h < HEADS; ++h) {
            float u = 0.f;
            for (int d = 0; d < 32; ++d)
                u += Wk_w[(size_t)(h * 32 + d) * C + c] * qv[h * 32 + d];
            U16[((size_t)g * SLOTS + s * HEADS + h) * C + c] =
                (unsigned short)f2b(u * RSQRT_DH);
        }
    }
}

// ---------------- fused MFMA kernel: QK^T + exp + denom + PV ----------------
__global__ __launch_bounds__(256, 2)
void k_fused(const float* __restrict__ nodes, const unsigned short* __restrict__ U16,
             const int* __restrict__ gstart, float* __restrict__ denom,
             float* __restrict__ Ypart) {
    __shared__ unsigned short x_nc[4 * CWK * XB];   // 33,792 B  [chunk][n][c]
    __shared__ unsigned short x_cn[2 * CNP];        // 40,960 B  [pair][c][n] swizzled
    __shared__ unsigned short e_lds[2 * SLOTS * EP];//  5,120 B  [pair][s][n]

    const int g = blockIdx.x / PF, pb = blockIdx.x % PF;
    const int t = threadIdx.x;
    const int wv = t >> 6;        // wave 0..3
    const int l  = t & 63;
    const int lr = l & 15;
    const int q  = l >> 4;

    const int glo = gstart[g], ghi = gstart[g + 1];
    const int len = ghi - glo;
    const int L = (len + PF - 1) / PF;
    const int lo = glo + pb * L;
    const int hi = min(lo + L, ghi);
    const int nr = (hi > lo) ? (hi - lo + RND - 1) / RND : 0;

    // ---- U_t fragments in registers (A-operand, both 16-row tiles) ----
    short8 ureg[2][8];
    {
        const unsigned short* ug = U16 + (size_t)g * SLOTS * C;
        #pragma unroll
        for (int st2 = 0; st2 < 2; ++st2)
            #pragma unroll
            for (int kt = 0; kt < 8; ++kt)
                ureg[st2][kt] = *(const short8*)&ug[(st2 * 16 + lr) * C + q * 8 + kt * 32];
    }

    const floatx4 z4 = {0.f, 0.f, 0.f, 0.f};
    floatx4 yacc[2][4];           // [st][ct]: Y[s=st*16+q*4+r][c=wv*64+ct*16+lr]
    #pragma unroll
    for (int a = 0; a < 2; ++a)
        #pragma unroll
        for (int b = 0; b < 4; ++b) yacc[a][b] = z4;
    float dsum[8];
    #pragma unroll
    for (int i = 0; i < 8; ++i) dsum[i] = 0.f;

    unsigned short* xw = &x_nc[wv * CWK * XB];
    const int p_own = wv >> 1, hw = wv & 1;

    // prefetch round 0
    float4 xr[CWK];
    if (nr > 0) {
        int base = lo + wv * CWK;
        #pragma unroll
        for (int i = 0; i < CWK; ++i) {
            int gn = base + i;
            xr[i] = (gn < hi) ? *(const float4*)&nodes[(size_t)gn * C + l * 4]
                              : make_float4(0.f, 0.f, 0.f, 0.f);
        }
    }

    for (int rd = 0; rd < nr; ++rd) {
        block_sync_lds();         // prev PV done reading x/e (no vmcnt drain!)

        // ---- write x_nc (node-major) ----
        #pragma unroll
        for (int i = 0; i < CWK; ++i) {
            uint2 w2;
            w2.x = pk_bf16(xr[i].x, xr[i].y);
            w2.y = pk_bf16(xr[i].z, xr[i].w);
            *(uint2*)&xw[i * XB + l * 4] = w2;
        }
        // ---- write x_cn (channel-major, 8-node blocks XOR-swizzled) ----
        #pragma unroll
        for (int jj = 0; jj < 4; ++jj) {
            const int c = 4 * l + jj;
            const int sz = ((c >> 2) ^ (c >> 4)) & 3;
            uint4 ulo, uhi;
            ulo.x = pk_bf16(fcomp(xr[0], jj), fcomp(xr[1], jj));
            ulo.y = pk_bf16(fcomp(xr[2], jj), fcomp(xr[3], jj));
            ulo.z = pk_bf16(fcomp(xr[4], jj), fcomp(xr[5], jj));
            ulo.w = pk_bf16(fcomp(xr[6], jj), fcomp(xr[7], jj));
            uhi.x = pk_bf16(fcomp(xr[8], jj), fcomp(xr[9], jj));
            uhi.y = pk_bf16(fcomp(xr[10], jj), fcomp(xr[11], jj));
            uhi.z = pk_bf16(fcomp(xr[12], jj), fcomp(xr[13], jj));
            uhi.w = pk_bf16(fcomp(xr[14], jj), fcomp(xr[15], jj));
            unsigned short* basep = &x_cn[p_own * CNP + c * ST];
            *(uint4*)&basep[((hw * 2 + 0) ^ sz) * 8] = ulo;   // nodes hw*16+0..7
            *(uint4*)&basep[((hw * 2 + 1) ^ sz) * 8] = uhi;   // nodes hw*16+8..15
        }
        // ---- prefetch next round (stays in flight across BOTH barriers) ----
        if (rd + 1 < nr) {
            int base = lo + (rd + 1) * RND + wv * CWK;
            #pragma unroll
            for (int i = 0; i < CWK; ++i) {
                int gn = base + i;
                xr[i] = (gn < hi) ? *(const float4*)&nodes[(size_t)gn * C + l * 4]
                                  : make_float4(0.f, 0.f, 0.f, 0.f);
            }
        }

        // ---- QK^T on own chunk (same-wave LDS dep, no barrier needed) ----
        floatx4 sacc0 = z4, sacc1 = z4;
        {
            const unsigned short* xrw = &xw[lr * XB + q * 8];
            #pragma unroll
            for (int kt = 0; kt < 8; ++kt) {
                short8 bx = *(const short8*)(xrw + kt * 32);
                sacc0 = __builtin_amdgcn_mfma_f32_16x16x32_bf16(ureg[0][kt], bx, sacc0, 0, 0, 0);
                sacc1 = __builtin_amdgcn_mfma_f32_16x16x32_bf16(ureg[1][kt], bx, sacc1, 0, 0, 0);
            }
        }

        // ---- exp, mask, denom, e_t write ----
        {
            int base = lo + rd * RND + wv * CWK;
            const bool valid = (base + lr) < hi;
            unsigned short* ew = &e_lds[p_own * SLOTS * EP + hw * 16 + lr];
            #pragma unroll
            for (int r = 0; r < 4; ++r) {
                float e0 = valid ? __expf(sacc0[r]) : 0.f;
                float e1 = valid ? __expf(sacc1[r]) : 0.f;
                dsum[r]     += e0;
                dsum[4 + r] += e1;
                ew[(q * 4 + r) * EP]      = (unsigned short)f2b(e0);
                ew[(16 + q * 4 + r) * EP] = (unsigned short)f2b(e1);
            }
        }
        block_sync_lds();         // all e_t + x_cn visible (vmem still counted)

        // ---- PV: Y[s][c-slice] += e_t[p] * x[p]  (K=32 per pair) ----
        #pragma unroll
        for (int p = 0; p < 2; ++p) {
            short8 pa0 = *(const short8*)&e_lds[(p * SLOTS + lr) * EP + q * 8];
            short8 pa1 = *(const short8*)&e_lds[(p * SLOTS + 16 + lr) * EP + q * 8];
            #pragma unroll
            for (int ct = 0; ct < 4; ++ct) {
                const int c = wv * 64 + ct * 16 + lr;
                const int sz = ((c >> 2) ^ (c >> 4)) & 3;
                short8 bx = *(const short8*)&x_cn[p * CNP + c * ST + ((q ^ sz) * 8)];
                yacc[0][ct] = __builtin_amdgcn_mfma_f32_16x16x32_bf16(pa0, bx, yacc[0][ct], 0, 0, 0);
                yacc[1][ct] = __builtin_amdgcn_mfma_f32_16x16x32_bf16(pa1, bx, yacc[1][ct], 0, 0, 0);
            }
        }
    }

    // ---- flush Y partials (also zero-fills when nr==0) ----
    {
        float* yg = &Ypart[(((size_t)g * PF + pb) * SLOTS) * C];
        #pragma unroll
        for (int st = 0; st < 2; ++st)
            #pragma unroll
            for (int ct = 0; ct < 4; ++ct)
                #pragma unroll
                for (int r = 0; r < 4; ++r)
                    yg[(st * 16 + q * 4 + r) * C + wv * 64 + ct * 16 + lr] = yacc[st][ct][r];
    }

    // ---- denom: reduce over 16 lanes (n-direction), atomics from lr==0 ----
    #pragma unroll
    for (int i = 0; i < 8; ++i) {
        float v = dsum[i];
        v += __shfl_xor(v, 1);
        v += __shfl_xor(v, 2);
        v += __shfl_xor(v, 4);
        v += __shfl_xor(v, 8);
        dsum[i] = v;
    }
    if (lr == 0 && nr > 0) {
        #pragma unroll
        for (int mt = 0; mt < 2; ++mt)
            #pragma unroll
            for (int r = 0; r < 4; ++r)
                atomicAdd(&denom[g * SLOTS + mt * 16 + q * 4 + r], dsum[mt * 4 + r]);
    }
}

// ---------------- epilogue: out = LN(elu(Wv*(Ysum/denom + cself*x) + bv) + stars)
__global__ void k_epilogue(const float* __restrict__ stars,
                           const float* __restrict__ Wv_w, const float* __restrict__ Wv_b,
                           const float* __restrict__ gamma, const float* __restrict__ beta,
                           const float* __restrict__ Ypart, const float* __restrict__ eself,
                           const float* __restrict__ denom, float* __restrict__ out) {
    __shared__ float xs[C];
    __shared__ float yl[HEADS * C];
    __shared__ float cs[HEADS], ivd[HEADS], scl[HEADS];
    __shared__ float rb[8];

    const int gs = blockIdx.x;
    const int g = gs >> 2, s = gs & 3;
    const int t = threadIdx.x;

    xs[t] = stars[gs * C + t];
    if (t < HEADS) {
        float dn = denom[g * SLOTS + s * HEADS + t];
        float iv = 1.f / (dn + 1e-16f);
        ivd[t] = iv;
        cs[t] = eself[g * SLOTS + s * HEADS + t] * iv;
        scl[t] = dn * iv;
    }
    __syncthreads();

    for (int i = t; i < HEADS * C; i += 256) {
        int h = i >> 8, j = i & 255;
        float sum = 0.f;
        #pragma unroll
        for (int pbi = 0; pbi < PF; ++pbi)
            sum += Ypart[(((size_t)g * PF + pbi) * SLOTS + s * HEADS + h) * C + j];
        yl[i] = sum * ivd[h] + cs[h] * xs[j];
    }
    __syncthreads();

    const int c = t, h = c >> 5;
    float a = 0.f;
    const float* wv = Wv_w + (size_t)c * C;
    const float* yh = &yl[h * C];
    #pragma unroll 4
    for (int j = 0; j < C; j += 4) {
        float4 w4 = *(const float4*)(wv + j);
        float4 y4 = *(const float4*)(yh + j);
        a += w4.x * y4.x + w4.y * y4.y + w4.z * y4.z + w4.w * y4.w;
    }
    a += Wv_b[c] * scl[h];

    float v = a > 0.f ? a : (__expf(a) - 1.f);     // ELU
    float r = v + xs[c];                            // residual

    float ssum = r;
    #pragma unroll
    for (int off = 32; off; off >>= 1) ssum += __shfl_down(ssum, off, 64);
    const int wid = t >> 6, lane = t & 63;
    if (lane == 0) rb[wid] = ssum;
    __syncthreads();
    const float mu = (rb[0] + rb[1] + rb[2] + rb[3]) * (1.f / 256.f);
    const float d = r - mu;
    float vsum = d * d;
    #pragma unroll
    for (int off = 32; off; off >>= 1) vsum += __shfl_down(vsum, off, 64);
    if (lane == 0) rb[4 + wid] = vsum;
    __syncthreads();
    const float var = (rb[4] + rb[5] + rb[6] + rb[7]) * (1.f / 256.f);
    out[gs * C + c] = d * rsqrtf(var + LN_EPS) * gamma[c] + beta[c];
}

// ---------------------------------------------------------------------------
extern "C" void kernel_launch(void* const* d_in, const int* in_sizes, int n_in,
                              void* d_out, int out_size, void* d_ws, size_t ws_size,
                              hipStream_t stream) {
    const float* stars = (const float*)d_in[0];
    const float* nodes = (const float*)d_in[1];
    const int*   batch = (const int*)d_in[2];
    const float* Wq_w  = (const float*)d_in[3];
    const float* Wq_b  = (const float*)d_in[4];
    const float* Wk_w  = (const float*)d_in[5];
    const float* Wk_b  = (const float*)d_in[6];
    const float* Wv_w  = (const float*)d_in[7];
    const float* Wv_b  = (const float*)d_in[8];
    const float* gamma = (const float*)d_in[9];
    const float* beta  = (const float*)d_in[10];

    const int N = in_sizes[1] / C;
    const int G = in_sizes[0] / (NUM_STAR * C);

    unsigned short* U16 = (unsigned short*)d_ws;                    // G*SLOTS*C ush
    float* eself = (float*)((char*)d_ws + (size_t)G * SLOTS * C * 2);
    float* denom = eself + (size_t)G * SLOTS;
    float* Ypart = denom + (size_t)G * SLOTS;                       // G*PF*SLOTS*C f32
    int*   gstart = (int*)(Ypart + (size_t)G * PF * SLOTS * C);     // G+1

    float* out = (float*)d_out;

    k_star_prep<<<G * NUM_STAR + 1, 256, 0, stream>>>(stars, Wq_w, Wq_b, Wk_w, Wk_b,
                                                      U16, eself, denom,
                                                      batch, N, G, gstart);
    k_fused<<<G * PF, 256, 0, stream>>>(nodes, U16, gstart, denom, Ypart);
    k_epilogue<<<G * NUM_STAR, 256, 0, stream>>>(stars, Wv_w, Wv_b, gamma, beta,
                                                 Ypart, eself, denom, out);
}